// Round 1
// baseline (104.036 us; speedup 1.0000x reference)
//
#include <hip/hip_runtime.h>
#include <hip/hip_bf16.h>

// FAVOR+ bidirectional linear attention, N=262144, D=64, fp32 in/out.
// Pass 1: K/V projections (bf16 MFMA) -> kv[64][64], ksum[64] via atomics.
// Pass 2: Q projection -> num = qp@kv, denom = qp.ksum, out = num/denom.

#define NPTS 262144
#define TILES (NPTS / 64)
#define EPS 1e-3f

typedef __attribute__((ext_vector_type(8))) short short8;   // 8 x bf16 (4 VGPRs)
typedef __attribute__((ext_vector_type(4))) float f32x4;

__device__ __forceinline__ unsigned short f2bf(float f) {
    unsigned u = __builtin_bit_cast(unsigned, f);
    u += 0x7FFFu + ((u >> 16) & 1u);           // round-to-nearest-even
    return (unsigned short)(u >> 16);
}

// B-fragment for 16x16x32 bf16 MFMA: lane holds B[k][col], k = kk*32 + lg*8 + e
__device__ __forceinline__ short8 load_bfrag(const float* __restrict__ W, int kk, int lg, int col) {
    short8 t;
    const float* p = W + (size_t)(kk * 32 + lg * 8) * 64 + col;
#pragma unroll
    for (int e = 0; e < 8; ++e) t[e] = (short)f2bf(p[(size_t)e * 64]);
    return t;
}

// A-fragments for a wave's 16 rows: lane l holds x[row0 + (l&15)][k], k = lg*8+e (a0), 32+lg*8+e (a1)
__device__ __forceinline__ void load_afrags(const float* __restrict__ xr, short8& a0, short8& a1) {
    float4 p0 = *(const float4*)(xr);
    float4 p1 = *(const float4*)(xr + 4);
    float4 p2 = *(const float4*)(xr + 32);
    float4 p3 = *(const float4*)(xr + 36);
    a0[0] = (short)f2bf(p0.x); a0[1] = (short)f2bf(p0.y); a0[2] = (short)f2bf(p0.z); a0[3] = (short)f2bf(p0.w);
    a0[4] = (short)f2bf(p1.x); a0[5] = (short)f2bf(p1.y); a0[6] = (short)f2bf(p1.z); a0[7] = (short)f2bf(p1.w);
    a1[0] = (short)f2bf(p2.x); a1[1] = (short)f2bf(p2.y); a1[2] = (short)f2bf(p2.z); a1[3] = (short)f2bf(p2.w);
    a1[4] = (short)f2bf(p3.x); a1[5] = (short)f2bf(p3.y); a1[6] = (short)f2bf(p3.z); a1[7] = (short)f2bf(p3.w);
}

__global__ __launch_bounds__(256, 2) void pass1_kernel(
    const float* __restrict__ x, const float* __restrict__ Wk, const float* __restrict__ bk,
    const float* __restrict__ Wv, const float* __restrict__ bv,
    float* __restrict__ kvg, float* __restrict__ ksg)
{
    // transposed staging: kpT[m][n], vT[d][n]; stride 72 -> 144B rows: 16B-aligned, 2-way bank alias max
    __shared__ unsigned short kpT[64][72];
    __shared__ unsigned short vT[64][72];

    const int tid = threadIdx.x;
    const int w = tid >> 6, l = tid & 63, l15 = l & 15, lg = l >> 4;

    short8 bkf[4][2], bvf[4][2];
#pragma unroll
    for (int j = 0; j < 4; ++j)
#pragma unroll
        for (int kk = 0; kk < 2; ++kk) {
            bkf[j][kk] = load_bfrag(Wk, kk, lg, j * 16 + l15);
            bvf[j][kk] = load_bfrag(Wv, kk, lg, j * 16 + l15);
        }
    float bkl[4], bvl[4];
#pragma unroll
    for (int j = 0; j < 4; ++j) { bkl[j] = bk[j * 16 + l15]; bvl[j] = bv[j * 16 + l15]; }

    f32x4 akv[4];
#pragma unroll
    for (int j = 0; j < 4; ++j) akv[j] = (f32x4){0.f, 0.f, 0.f, 0.f};
    float ks[4] = {0.f, 0.f, 0.f, 0.f};

    const int tpb = TILES / gridDim.x;
    const int t0 = blockIdx.x * tpb;
    for (int t = 0; t < tpb; ++t) {
        const int row0 = (t0 + t) * 64 + w * 16;
        const float* xr = x + (size_t)(row0 + l15) * 64 + lg * 8;
        short8 a0, a1;
        load_afrags(xr, a0, a1);

        const int nbase = w * 16 + lg * 4;     // n index of this lane's 4 C-rows
#pragma unroll
        for (int j = 0; j < 4; ++j) {
            f32x4 z = (f32x4){0.f, 0.f, 0.f, 0.f};
            f32x4 ak = __builtin_amdgcn_mfma_f32_16x16x32_bf16(a0, bkf[j][0], z, 0, 0, 0);
            ak = __builtin_amdgcn_mfma_f32_16x16x32_bf16(a1, bkf[j][1], ak, 0, 0, 0);
            f32x4 av = __builtin_amdgcn_mfma_f32_16x16x32_bf16(a0, bvf[j][0], z, 0, 0, 0);
            av = __builtin_amdgcn_mfma_f32_16x16x32_bf16(a1, bvf[j][1], av, 0, 0, 0);
            unsigned short h[4], g[4];
#pragma unroll
            for (int r = 0; r < 4; ++r) {
                float kp = fmaxf(ak[r] + bkl[j], 0.f) + EPS;
                ks[j] += kp;
                h[r] = f2bf(kp);
                g[r] = f2bf(av[r] + bvl[j]);
            }
            uint2 hp, gp;
            hp.x = (unsigned)h[0] | ((unsigned)h[1] << 16);
            hp.y = (unsigned)h[2] | ((unsigned)h[3] << 16);
            gp.x = (unsigned)g[0] | ((unsigned)g[1] << 16);
            gp.y = (unsigned)g[2] | ((unsigned)g[3] << 16);
            *(uint2*)&kpT[j * 16 + l15][nbase] = hp;   // kpT[m][n]
            *(uint2*)&vT[j * 16 + l15][nbase] = gp;    // vT[d][n]
        }
        __syncthreads();
        // kv[m][d] += sum_n kp[n][m] * v[n][d]; wave w owns m in [w*16, w*16+16)
        short8 ka0 = *(const short8*)&kpT[w * 16 + l15][lg * 8];
        short8 ka1 = *(const short8*)&kpT[w * 16 + l15][32 + lg * 8];
#pragma unroll
        for (int j = 0; j < 4; ++j) {
            short8 vb0 = *(const short8*)&vT[j * 16 + l15][lg * 8];
            short8 vb1 = *(const short8*)&vT[j * 16 + l15][32 + lg * 8];
            akv[j] = __builtin_amdgcn_mfma_f32_16x16x32_bf16(ka0, vb0, akv[j], 0, 0, 0);
            akv[j] = __builtin_amdgcn_mfma_f32_16x16x32_bf16(ka1, vb1, akv[j], 0, 0, 0);
        }
        __syncthreads();
    }
    // flush partials: C-layout row m = w*16 + lg*4 + r, col d = j*16 + l15
#pragma unroll
    for (int j = 0; j < 4; ++j)
#pragma unroll
        for (int r = 0; r < 4; ++r)
            unsafeAtomicAdd(&kvg[(size_t)(w * 16 + lg * 4 + r) * 64 + j * 16 + l15], akv[j][r]);
#pragma unroll
    for (int j = 0; j < 4; ++j) {
        float s = ks[j];
        s += __shfl_xor(s, 16, 64);
        s += __shfl_xor(s, 32, 64);
        if (lg == 0) unsafeAtomicAdd(&ksg[j * 16 + l15], s);
    }
}

__global__ __launch_bounds__(256, 2) void pass2_kernel(
    const float* __restrict__ x, const float* __restrict__ Wq, const float* __restrict__ bq,
    const float* __restrict__ kvg, const float* __restrict__ ksg,
    float* __restrict__ out)
{
    __shared__ unsigned short qpL[64][72];    // qp[n][m], m contiguous

    const int tid = threadIdx.x;
    const int w = tid >> 6, l = tid & 63, l15 = l & 15, lg = l >> 4;

    short8 bqf[4][2], kvf[4][2];
#pragma unroll
    for (int j = 0; j < 4; ++j)
#pragma unroll
        for (int kk = 0; kk < 2; ++kk) {
            bqf[j][kk] = load_bfrag(Wq, kk, lg, j * 16 + l15);
            kvf[j][kk] = load_bfrag(kvg, kk, lg, j * 16 + l15);   // kv as B operand
        }
    float ksl[4], bql[4];
#pragma unroll
    for (int j = 0; j < 4; ++j) { ksl[j] = ksg[j * 16 + l15]; bql[j] = bq[j * 16 + l15]; }

    const int tpb = TILES / gridDim.x;
    const int t0 = blockIdx.x * tpb;
    for (int t = 0; t < tpb; ++t) {
        const int row0 = (t0 + t) * 64 + w * 16;
        const float* xr = x + (size_t)(row0 + l15) * 64 + lg * 8;
        short8 a0, a1;
        load_afrags(xr, a0, a1);

        float qp[4][4];
#pragma unroll
        for (int j = 0; j < 4; ++j) {
            f32x4 z = (f32x4){0.f, 0.f, 0.f, 0.f};
            f32x4 aq = __builtin_amdgcn_mfma_f32_16x16x32_bf16(a0, bqf[j][0], z, 0, 0, 0);
            aq = __builtin_amdgcn_mfma_f32_16x16x32_bf16(a1, bqf[j][1], aq, 0, 0, 0);
#pragma unroll
            for (int r = 0; r < 4; ++r) qp[j][r] = fmaxf(aq[r] + bql[j], 0.f) + EPS;
        }
        // denom[row] = sum_m qp[row][m]*ksum[m]; butterfly over the 16 lanes of each row-group
        float dp[4];
#pragma unroll
        for (int r = 0; r < 4; ++r)
            dp[r] = qp[0][r] * ksl[0] + qp[1][r] * ksl[1] + qp[2][r] * ksl[2] + qp[3][r] * ksl[3];
#pragma unroll
        for (int mask = 1; mask <= 8; mask <<= 1)
#pragma unroll
            for (int r = 0; r < 4; ++r) dp[r] += __shfl_xor(dp[r], mask, 64);

        const int nb = w * 16 + lg * 4;
#pragma unroll
        for (int j = 0; j < 4; ++j)
#pragma unroll
            for (int r = 0; r < 4; ++r)
                qpL[nb + r][j * 16 + l15] = f2bf(qp[j][r]);
        __syncthreads();

        short8 an0 = *(const short8*)&qpL[w * 16 + l15][lg * 8];
        short8 an1 = *(const short8*)&qpL[w * 16 + l15][32 + lg * 8];
#pragma unroll
        for (int j = 0; j < 4; ++j) {
            f32x4 z = (f32x4){0.f, 0.f, 0.f, 0.f};
            f32x4 nm = __builtin_amdgcn_mfma_f32_16x16x32_bf16(an0, kvf[j][0], z, 0, 0, 0);
            nm = __builtin_amdgcn_mfma_f32_16x16x32_bf16(an1, kvf[j][1], nm, 0, 0, 0);
#pragma unroll
            for (int r = 0; r < 4; ++r)
                out[(size_t)(row0 + lg * 4 + r) * 64 + j * 16 + l15] = nm[r] / dp[r];
        }
        __syncthreads();
    }
}

extern "C" void kernel_launch(void* const* d_in, const int* in_sizes, int n_in,
                              void* d_out, int out_size, void* d_ws, size_t ws_size,
                              hipStream_t stream)
{
    const float* x  = (const float*)d_in[0];
    const float* Wq = (const float*)d_in[1];
    const float* bq = (const float*)d_in[2];
    const float* Wk = (const float*)d_in[3];
    const float* bk = (const float*)d_in[4];
    const float* Wv = (const float*)d_in[5];
    const float* bv = (const float*)d_in[6];
    float* out = (float*)d_out;
    float* kvg = (float*)d_ws;            // 64*64 f32
    float* ksg = kvg + 64 * 64;           // 64 f32

    hipMemsetAsync(d_ws, 0, (64 * 64 + 64) * sizeof(float), stream);
    hipLaunchKernelGGL(pass1_kernel, dim3(512), dim3(256), 0, stream,
                       x, Wk, bk, Wv, bv, kvg, ksg);
    hipLaunchKernelGGL(pass2_kernel, dim3(1024), dim3(256), 0, stream,
                       x, Wq, bq, kvg, ksg, out);
}

// Round 2
// 75.495 us; speedup vs baseline: 1.3781x; 1.3781x over previous
//
#include <hip/hip_runtime.h>
#include <hip/hip_bf16.h>

// FAVOR+ bidirectional linear attention, N=262144, D=64, fp32 in/out.
// Pass 1: K/V projections (bf16 MFMA) -> kv[8][64][64], ksum[8][64] via slotted atomics.
// Pass 2: reduce slots, Q projection -> num = qp@kv, denom = qp.ksum, out = num/denom.

#define NPTS 262144
#define TILES (NPTS / 64)      // 4096
#define GRID1 1024
#define TPB1 (TILES / GRID1)   // 4
#define GRID2 1024
#define TPB2 (TILES / GRID2)   // 4
#define NSLOT 8
#define EPS 1e-3f

typedef __attribute__((ext_vector_type(8))) short short8;   // 8 x bf16 (4 VGPRs)
typedef __attribute__((ext_vector_type(4))) float f32x4;

__device__ __forceinline__ unsigned short f2bf(float f) {
    unsigned u = __builtin_bit_cast(unsigned, f);
    u += 0x7FFFu + ((u >> 16) & 1u);           // round-to-nearest-even
    return (unsigned short)(u >> 16);
}

// B-fragment gather from global f32 row-major [64][64]: lane holds B[k][col], k = kk*32 + lg*8 + e
__device__ __forceinline__ short8 load_bfrag(const float* __restrict__ W, int kk, int lg, int col) {
    short8 t;
    const float* p = W + (size_t)(kk * 32 + lg * 8) * 64 + col;
#pragma unroll
    for (int e = 0; e < 8; ++e) t[e] = (short)f2bf(p[(size_t)e * 64]);
    return t;
}

__device__ __forceinline__ short8 cvt8(float4 p0, float4 p1) {
    short8 a;
    a[0] = (short)f2bf(p0.x); a[1] = (short)f2bf(p0.y); a[2] = (short)f2bf(p0.z); a[3] = (short)f2bf(p0.w);
    a[4] = (short)f2bf(p1.x); a[5] = (short)f2bf(p1.y); a[6] = (short)f2bf(p1.z); a[7] = (short)f2bf(p1.w);
    return a;
}

// barrier that drains LDS ops only (keeps global prefetch loads in flight)
__device__ __forceinline__ void lds_barrier() {
    asm volatile("s_waitcnt lgkmcnt(0)" ::: "memory");
    __builtin_amdgcn_s_barrier();
}

__global__ __launch_bounds__(256, 4) void pass1_kernel(
    const float* __restrict__ x, const float* __restrict__ Wk, const float* __restrict__ bk,
    const float* __restrict__ Wv, const float* __restrict__ bv,
    float* __restrict__ kvp, float* __restrict__ ksp)
{
    __shared__ unsigned short kpT[64][72];       // kp transposed [m][n]
    __shared__ unsigned short vT[64][72];        // v  transposed [d][n]
    __shared__ unsigned short wkF[8][64][8];     // Wk B-frags, frag-order: [j*2+kk][lane][e]
    __shared__ unsigned short wvF[8][64][8];     // Wv B-frags

    const int tid = threadIdx.x;
    const int w = tid >> 6, l = tid & 63, l15 = l & 15, lg = l >> 4;

    // build weight frags once per block (each wave builds 4 of the 16 entries)
    {
        const float* W = (w < 2) ? Wk : Wv;
        int jbase = (w & 1) * 2;
#pragma unroll
        for (int jj = 0; jj < 2; ++jj)
#pragma unroll
            for (int kk = 0; kk < 2; ++kk) {
                short8 f = load_bfrag(W, kk, lg, (jbase + jj) * 16 + l15);
                if (w < 2) *(short8*)&wkF[(jbase + jj) * 2 + kk][l][0] = f;
                else       *(short8*)&wvF[(jbase + jj) * 2 + kk][l][0] = f;
            }
    }
    float bkl[4], bvl[4];
#pragma unroll
    for (int j = 0; j < 4; ++j) { bkl[j] = bk[j * 16 + l15]; bvl[j] = bv[j * 16 + l15]; }

    f32x4 akv[4];
#pragma unroll
    for (int j = 0; j < 4; ++j) akv[j] = (f32x4){0.f, 0.f, 0.f, 0.f};
    float ks[4] = {0.f, 0.f, 0.f, 0.f};

    lds_barrier();   // frags ready

    const int t0 = blockIdx.x * TPB1;
    const float* xbase = x + ((size_t)t0 * 64 + w * 16 + l15) * 64 + lg * 8;
    float4 c0 = *(const float4*)(xbase + 0);
    float4 c1 = *(const float4*)(xbase + 4);
    float4 c2 = *(const float4*)(xbase + 32);
    float4 c3 = *(const float4*)(xbase + 36);

#pragma unroll
    for (int t = 0; t < TPB1; ++t) {
        // prefetch next tile (safe re-read of current tile on last iter)
        const float* xn = xbase + (size_t)((t + 1 < TPB1) ? (t + 1) : t) * 4096;
        float4 n0 = *(const float4*)(xn + 0);
        float4 n1 = *(const float4*)(xn + 4);
        float4 n2 = *(const float4*)(xn + 32);
        float4 n3 = *(const float4*)(xn + 36);

        short8 a0 = cvt8(c0, c1);
        short8 a1 = cvt8(c2, c3);

        const int nbase = w * 16 + lg * 4;     // n index of this lane's 4 C-rows
#pragma unroll
        for (int j = 0; j < 4; ++j) {
            short8 bk0 = *(const short8*)&wkF[j * 2 + 0][l][0];
            short8 bk1 = *(const short8*)&wkF[j * 2 + 1][l][0];
            short8 bv0 = *(const short8*)&wvF[j * 2 + 0][l][0];
            short8 bv1 = *(const short8*)&wvF[j * 2 + 1][l][0];
            f32x4 z = (f32x4){0.f, 0.f, 0.f, 0.f};
            f32x4 ak = __builtin_amdgcn_mfma_f32_16x16x32_bf16(a0, bk0, z, 0, 0, 0);
            ak = __builtin_amdgcn_mfma_f32_16x16x32_bf16(a1, bk1, ak, 0, 0, 0);
            f32x4 av = __builtin_amdgcn_mfma_f32_16x16x32_bf16(a0, bv0, z, 0, 0, 0);
            av = __builtin_amdgcn_mfma_f32_16x16x32_bf16(a1, bv1, av, 0, 0, 0);
            unsigned short h[4], g[4];
#pragma unroll
            for (int r = 0; r < 4; ++r) {
                float kp = fmaxf(ak[r] + bkl[j], 0.f) + EPS;
                ks[j] += kp;
                h[r] = f2bf(kp);
                g[r] = f2bf(av[r] + bvl[j]);
            }
            uint2 hp, gp;
            hp.x = (unsigned)h[0] | ((unsigned)h[1] << 16);
            hp.y = (unsigned)h[2] | ((unsigned)h[3] << 16);
            gp.x = (unsigned)g[0] | ((unsigned)g[1] << 16);
            gp.y = (unsigned)g[2] | ((unsigned)g[3] << 16);
            *(uint2*)&kpT[j * 16 + l15][nbase] = hp;   // kpT[m][n]
            *(uint2*)&vT[j * 16 + l15][nbase] = gp;    // vT[d][n]
        }
        lds_barrier();
        // kv[m][d] += sum_n kp[n][m] * v[n][d]; wave w owns m in [w*16, w*16+16)
        short8 ka0 = *(const short8*)&kpT[w * 16 + l15][lg * 8];
        short8 ka1 = *(const short8*)&kpT[w * 16 + l15][32 + lg * 8];
#pragma unroll
        for (int j = 0; j < 4; ++j) {
            short8 vb0 = *(const short8*)&vT[j * 16 + l15][lg * 8];
            short8 vb1 = *(const short8*)&vT[j * 16 + l15][32 + lg * 8];
            akv[j] = __builtin_amdgcn_mfma_f32_16x16x32_bf16(ka0, vb0, akv[j], 0, 0, 0);
            akv[j] = __builtin_amdgcn_mfma_f32_16x16x32_bf16(ka1, vb1, akv[j], 0, 0, 0);
        }
        lds_barrier();
        c0 = n0; c1 = n1; c2 = n2; c3 = n3;
    }

    // flush partials into slot (blockIdx & 7) to cut per-address collisions 8x
    float* kvs = kvp + (size_t)(blockIdx.x & (NSLOT - 1)) * 64 * 64;
    float* kss = ksp + (size_t)(blockIdx.x & (NSLOT - 1)) * 64;
#pragma unroll
    for (int j = 0; j < 4; ++j)
#pragma unroll
        for (int r = 0; r < 4; ++r)
            unsafeAtomicAdd(&kvs[(size_t)(w * 16 + lg * 4 + r) * 64 + j * 16 + l15], akv[j][r]);
#pragma unroll
    for (int j = 0; j < 4; ++j) {
        float s = ks[j];
        s += __shfl_xor(s, 16, 64);
        s += __shfl_xor(s, 32, 64);
        if (lg == 0) unsafeAtomicAdd(&kss[j * 16 + l15], s);
    }
}

__global__ __launch_bounds__(256, 4) void pass2_kernel(
    const float* __restrict__ x, const float* __restrict__ Wq, const float* __restrict__ bq,
    const float* __restrict__ kvp, const float* __restrict__ ksp,
    float* __restrict__ out)
{
    __shared__ unsigned short qpL[64][72];     // qp staging; init-phase reuse as linear kv bf16 [64*64]
    __shared__ unsigned short wqF[8][64][8];   // Wq B-frags
    __shared__ unsigned short kvF[8][64][8];   // kv B-frags
    __shared__ float ksL[64];

    const int tid = threadIdx.x;
    const int w = tid >> 6, l = tid & 63, l15 = l & 15, lg = l >> 4;

    // 1) reduce the 8 kv slots -> linear bf16 into qpL storage
    {
        float acc[16] = {0.f, 0.f, 0.f, 0.f, 0.f, 0.f, 0.f, 0.f,
                         0.f, 0.f, 0.f, 0.f, 0.f, 0.f, 0.f, 0.f};
        const float* p = kvp + (size_t)tid * 16;
#pragma unroll
        for (int s = 0; s < NSLOT; ++s) {
#pragma unroll
            for (int v = 0; v < 4; ++v) {
                float4 f = *(const float4*)(p + (size_t)s * 4096 + v * 4);
                acc[v * 4 + 0] += f.x; acc[v * 4 + 1] += f.y;
                acc[v * 4 + 2] += f.z; acc[v * 4 + 3] += f.w;
            }
        }
        unsigned short* kvStage = &qpL[0][0];
        unsigned h[8];
#pragma unroll
        for (int e = 0; e < 8; ++e)
            h[e] = (unsigned)f2bf(acc[2 * e]) | ((unsigned)f2bf(acc[2 * e + 1]) << 16);
        uint4 w0 = {h[0], h[1], h[2], h[3]};
        uint4 w1 = {h[4], h[5], h[6], h[7]};
        *(uint4*)&kvStage[tid * 16 + 0] = w0;
        *(uint4*)&kvStage[tid * 16 + 8] = w1;
        if (tid < 64) {
            float s = 0.f;
#pragma unroll
            for (int sl = 0; sl < NSLOT; ++sl) s += ksp[sl * 64 + tid];
            ksL[tid] = s;
        }
    }
    // 2) Wq frags from global (wave w builds j = w)
    {
#pragma unroll
        for (int kk = 0; kk < 2; ++kk) {
            short8 f = load_bfrag(Wq, kk, lg, w * 16 + l15);
            *(short8*)&wqF[w * 2 + kk][l][0] = f;
        }
    }
    float bql[4];
#pragma unroll
    for (int j = 0; j < 4; ++j) bql[j] = bq[j * 16 + l15];

    lds_barrier();   // kv stage + ksL ready

    // 3) kv frags from staged linear kv (wave w builds j = w)
    {
        const unsigned short* kvStage = &qpL[0][0];
#pragma unroll
        for (int kk = 0; kk < 2; ++kk) {
            short8 f;
#pragma unroll
            for (int e = 0; e < 8; ++e)
                f[e] = (short)kvStage[(kk * 32 + lg * 8 + e) * 64 + w * 16 + l15];
            *(short8*)&kvF[w * 2 + kk][l][0] = f;
        }
    }
    float ksl[4];
#pragma unroll
    for (int j = 0; j < 4; ++j) ksl[j] = ksL[j * 16 + l15];

    lds_barrier();   // kvF done, qpL free for reuse

    const int t0 = blockIdx.x * TPB2;
    const float* xbase = x + ((size_t)t0 * 64 + w * 16 + l15) * 64 + lg * 8;
    float4 c0 = *(const float4*)(xbase + 0);
    float4 c1 = *(const float4*)(xbase + 4);
    float4 c2 = *(const float4*)(xbase + 32);
    float4 c3 = *(const float4*)(xbase + 36);

#pragma unroll
    for (int t = 0; t < TPB2; ++t) {
        const float* xn = xbase + (size_t)((t + 1 < TPB2) ? (t + 1) : t) * 4096;
        float4 n0 = *(const float4*)(xn + 0);
        float4 n1 = *(const float4*)(xn + 4);
        float4 n2 = *(const float4*)(xn + 32);
        float4 n3 = *(const float4*)(xn + 36);

        short8 a0 = cvt8(c0, c1);
        short8 a1 = cvt8(c2, c3);

        float qp[4][4];
#pragma unroll
        for (int j = 0; j < 4; ++j) {
            short8 bq0 = *(const short8*)&wqF[j * 2 + 0][l][0];
            short8 bq1 = *(const short8*)&wqF[j * 2 + 1][l][0];
            f32x4 z = (f32x4){0.f, 0.f, 0.f, 0.f};
            f32x4 aq = __builtin_amdgcn_mfma_f32_16x16x32_bf16(a0, bq0, z, 0, 0, 0);
            aq = __builtin_amdgcn_mfma_f32_16x16x32_bf16(a1, bq1, aq, 0, 0, 0);
#pragma unroll
            for (int r = 0; r < 4; ++r) qp[j][r] = fmaxf(aq[r] + bql[j], 0.f) + EPS;
        }
        // denom[row] = sum_m qp[row][m]*ksum[m]; butterfly across the 16 col-lanes
        float dp[4];
#pragma unroll
        for (int r = 0; r < 4; ++r)
            dp[r] = qp[0][r] * ksl[0] + qp[1][r] * ksl[1] + qp[2][r] * ksl[2] + qp[3][r] * ksl[3];
#pragma unroll
        for (int mask = 1; mask <= 8; mask <<= 1)
#pragma unroll
            for (int r = 0; r < 4; ++r) dp[r] += __shfl_xor(dp[r], mask, 64);

        const int nb = w * 16 + lg * 4;
#pragma unroll
        for (int j = 0; j < 4; ++j)
#pragma unroll
            for (int r = 0; r < 4; ++r)
                qpL[nb + r][j * 16 + l15] = f2bf(qp[j][r]);
        lds_barrier();

        short8 an0 = *(const short8*)&qpL[w * 16 + l15][lg * 8];
        short8 an1 = *(const short8*)&qpL[w * 16 + l15][32 + lg * 8];
        float inv[4];
#pragma unroll
        for (int r = 0; r < 4; ++r) inv[r] = __builtin_amdgcn_rcpf(dp[r]);
        const int row0 = (t0 + t) * 64 + w * 16;
#pragma unroll
        for (int j = 0; j < 4; ++j) {
            short8 kv0 = *(const short8*)&kvF[j * 2 + 0][l][0];
            short8 kv1 = *(const short8*)&kvF[j * 2 + 1][l][0];
            f32x4 z = (f32x4){0.f, 0.f, 0.f, 0.f};
            f32x4 nm = __builtin_amdgcn_mfma_f32_16x16x32_bf16(an0, kv0, z, 0, 0, 0);
            nm = __builtin_amdgcn_mfma_f32_16x16x32_bf16(an1, kv1, nm, 0, 0, 0);
#pragma unroll
            for (int r = 0; r < 4; ++r)
                out[(size_t)(row0 + lg * 4 + r) * 64 + j * 16 + l15] = nm[r] * inv[r];
        }
        lds_barrier();
        c0 = n0; c1 = n1; c2 = n2; c3 = n3;
    }
}

extern "C" void kernel_launch(void* const* d_in, const int* in_sizes, int n_in,
                              void* d_out, int out_size, void* d_ws, size_t ws_size,
                              hipStream_t stream)
{
    const float* x  = (const float*)d_in[0];
    const float* Wq = (const float*)d_in[1];
    const float* bq = (const float*)d_in[2];
    const float* Wk = (const float*)d_in[3];
    const float* bk = (const float*)d_in[4];
    const float* Wv = (const float*)d_in[5];
    const float* bv = (const float*)d_in[6];
    float* out = (float*)d_out;
    float* kvp = (float*)d_ws;                       // 8 * 64*64 f32
    float* ksp = kvp + (size_t)NSLOT * 64 * 64;      // 8 * 64   f32

    hipMemsetAsync(d_ws, 0, (size_t)NSLOT * (64 * 64 + 64) * sizeof(float), stream);
    hipLaunchKernelGGL(pass1_kernel, dim3(GRID1), dim3(256), 0, stream,
                       x, Wk, bk, Wv, bv, kvp, ksp);
    hipLaunchKernelGGL(pass2_kernel, dim3(GRID2), dim3(256), 0, stream,
                       x, Wq, bq, kvp, ksp, out);
}

// Round 3
// 61.691 us; speedup vs baseline: 1.6864x; 1.2238x over previous
//
#include <hip/hip_runtime.h>
#include <hip/hip_bf16.h>

// FAVOR+ bidirectional linear attention, N=262144, D=64, fp32 in/out.
// Pass 1: K/V projections (bf16 MFMA) -> per-block partial kv/ksum (plain stores).
// Reduce: sum 512 partials -> final kv[64][64], ksum[64].
// Pass 2: Q projection -> num = qp@kv, denom = qp.ksum, out = num/denom.

#define NPTS 262144
#define TILES (NPTS / 64)      // 4096
#define GRID1 512
#define TPB1 (TILES / GRID1)   // 8
#define GRID2 1024
#define TPB2 (TILES / GRID2)   // 4
#define EPS 1e-3f

typedef __attribute__((ext_vector_type(8))) short short8;   // 8 x bf16 (4 VGPRs)
typedef __attribute__((ext_vector_type(4))) float f32x4;

__device__ __forceinline__ unsigned short f2bf(float f) {
    unsigned u = __builtin_bit_cast(unsigned, f);
    u += 0x7FFFu + ((u >> 16) & 1u);           // round-to-nearest-even
    return (unsigned short)(u >> 16);
}

// B-fragment gather from global f32 row-major [64][64]: lane holds B[k][col], k = kk*32 + lg*8 + e
__device__ __forceinline__ short8 load_bfrag(const float* __restrict__ W, int kk, int lg, int col) {
    short8 t;
    const float* p = W + (size_t)(kk * 32 + lg * 8) * 64 + col;
#pragma unroll
    for (int e = 0; e < 8; ++e) t[e] = (short)f2bf(p[(size_t)e * 64]);
    return t;
}

__device__ __forceinline__ short8 cvt8(float4 p0, float4 p1) {
    short8 a;
    a[0] = (short)f2bf(p0.x); a[1] = (short)f2bf(p0.y); a[2] = (short)f2bf(p0.z); a[3] = (short)f2bf(p0.w);
    a[4] = (short)f2bf(p1.x); a[5] = (short)f2bf(p1.y); a[6] = (short)f2bf(p1.z); a[7] = (short)f2bf(p1.w);
    return a;
}

// barrier that drains LDS ops only (keeps global prefetch loads in flight)
__device__ __forceinline__ void lds_barrier() {
    asm volatile("s_waitcnt lgkmcnt(0)" ::: "memory");
    __builtin_amdgcn_s_barrier();
}

__global__ __launch_bounds__(256, 2) void pass1_kernel(
    const float* __restrict__ x, const float* __restrict__ Wk, const float* __restrict__ bk,
    const float* __restrict__ Wv, const float* __restrict__ bv,
    float* __restrict__ kvPart, float* __restrict__ ksPart)
{
    __shared__ unsigned short kpT[64][72];       // kp transposed [m][n]
    __shared__ unsigned short vT[64][72];        // v  transposed [d][n]
    __shared__ unsigned short wkF[8][64][8];     // Wk B-frags, frag-order: [j*2+kk][lane][e]
    __shared__ unsigned short wvF[8][64][8];     // Wv B-frags

    const int tid = threadIdx.x;
    const int w = tid >> 6, l = tid & 63, l15 = l & 15, lg = l >> 4;

    // build weight frags once per block (each wave builds 4 of the 16 entries)
    {
        const float* W = (w < 2) ? Wk : Wv;
        int jbase = (w & 1) * 2;
#pragma unroll
        for (int jj = 0; jj < 2; ++jj)
#pragma unroll
            for (int kk = 0; kk < 2; ++kk) {
                short8 f = load_bfrag(W, kk, lg, (jbase + jj) * 16 + l15);
                if (w < 2) *(short8*)&wkF[(jbase + jj) * 2 + kk][l][0] = f;
                else       *(short8*)&wvF[(jbase + jj) * 2 + kk][l][0] = f;
            }
    }
    float bkl[4], bvl[4];
#pragma unroll
    for (int j = 0; j < 4; ++j) { bkl[j] = bk[j * 16 + l15]; bvl[j] = bv[j * 16 + l15]; }

    f32x4 akv[4];
#pragma unroll
    for (int j = 0; j < 4; ++j) akv[j] = (f32x4){0.f, 0.f, 0.f, 0.f};
    float ks[4] = {0.f, 0.f, 0.f, 0.f};

    lds_barrier();   // frags ready

    const int t0 = blockIdx.x * TPB1;
    const float* xbase = x + ((size_t)t0 * 64 + w * 16 + l15) * 64 + lg * 8;
    float4 c0 = *(const float4*)(xbase + 0);
    float4 c1 = *(const float4*)(xbase + 4);
    float4 c2 = *(const float4*)(xbase + 32);
    float4 c3 = *(const float4*)(xbase + 36);

    for (int t = 0; t < TPB1; ++t) {
        // prefetch next tile (safe re-read of current tile on last iter)
        const float* xn = xbase + (size_t)((t + 1 < TPB1) ? (t + 1) : t) * 4096;
        float4 n0 = *(const float4*)(xn + 0);
        float4 n1 = *(const float4*)(xn + 4);
        float4 n2 = *(const float4*)(xn + 32);
        float4 n3 = *(const float4*)(xn + 36);

        short8 a0 = cvt8(c0, c1);
        short8 a1 = cvt8(c2, c3);

        const int nbase = w * 16 + lg * 4;     // n index of this lane's 4 C-rows
#pragma unroll
        for (int j = 0; j < 4; ++j) {
            short8 bk0 = *(const short8*)&wkF[j * 2 + 0][l][0];
            short8 bk1 = *(const short8*)&wkF[j * 2 + 1][l][0];
            short8 bv0 = *(const short8*)&wvF[j * 2 + 0][l][0];
            short8 bv1 = *(const short8*)&wvF[j * 2 + 1][l][0];
            f32x4 z = (f32x4){0.f, 0.f, 0.f, 0.f};
            f32x4 ak = __builtin_amdgcn_mfma_f32_16x16x32_bf16(a0, bk0, z, 0, 0, 0);
            ak = __builtin_amdgcn_mfma_f32_16x16x32_bf16(a1, bk1, ak, 0, 0, 0);
            f32x4 av = __builtin_amdgcn_mfma_f32_16x16x32_bf16(a0, bv0, z, 0, 0, 0);
            av = __builtin_amdgcn_mfma_f32_16x16x32_bf16(a1, bv1, av, 0, 0, 0);
            unsigned short h[4], g[4];
#pragma unroll
            for (int r = 0; r < 4; ++r) {
                float kp = fmaxf(ak[r] + bkl[j], 0.f) + EPS;
                ks[j] += kp;
                h[r] = f2bf(kp);
                g[r] = f2bf(av[r] + bvl[j]);
            }
            uint2 hp, gp;
            hp.x = (unsigned)h[0] | ((unsigned)h[1] << 16);
            hp.y = (unsigned)h[2] | ((unsigned)h[3] << 16);
            gp.x = (unsigned)g[0] | ((unsigned)g[1] << 16);
            gp.y = (unsigned)g[2] | ((unsigned)g[3] << 16);
            *(uint2*)&kpT[j * 16 + l15][nbase] = hp;   // kpT[m][n]
            *(uint2*)&vT[j * 16 + l15][nbase] = gp;    // vT[d][n]
        }
        lds_barrier();
        // kv[m][d] += sum_n kp[n][m] * v[n][d]; wave w owns m in [w*16, w*16+16)
        short8 ka0 = *(const short8*)&kpT[w * 16 + l15][lg * 8];
        short8 ka1 = *(const short8*)&kpT[w * 16 + l15][32 + lg * 8];
#pragma unroll
        for (int j = 0; j < 4; ++j) {
            short8 vb0 = *(const short8*)&vT[j * 16 + l15][lg * 8];
            short8 vb1 = *(const short8*)&vT[j * 16 + l15][32 + lg * 8];
            akv[j] = __builtin_amdgcn_mfma_f32_16x16x32_bf16(ka0, vb0, akv[j], 0, 0, 0);
            akv[j] = __builtin_amdgcn_mfma_f32_16x16x32_bf16(ka1, vb1, akv[j], 0, 0, 0);
        }
        lds_barrier();
        c0 = n0; c1 = n1; c2 = n2; c3 = n3;
    }

    // flush per-block partials with plain stores (no atomics, no zero-init needed)
    float* kvs = kvPart + (size_t)blockIdx.x * 4096;
#pragma unroll
    for (int j = 0; j < 4; ++j)
#pragma unroll
        for (int r = 0; r < 4; ++r)
            kvs[(size_t)(w * 16 + lg * 4 + r) * 64 + j * 16 + l15] = akv[j][r];
    // ksum partial per (block, wave): reduce over lg within wave, store 64 floats
#pragma unroll
    for (int j = 0; j < 4; ++j) {
        float s = ks[j];
        s += __shfl_xor(s, 16, 64);
        s += __shfl_xor(s, 32, 64);
        if (lg == 0) ksPart[(size_t)blockIdx.x * 256 + w * 64 + j * 16 + l15] = s;
    }
}

// 65 blocks: b<64 -> kv outputs b*64..b*64+63; b==64 -> ksum outputs 0..63
__global__ __launch_bounds__(256, 4) void reduce_kernel(
    const float* __restrict__ kvPart, const float* __restrict__ ksPart,
    float* __restrict__ kvFin, float* __restrict__ ksFin)
{
    __shared__ float red[4][64];
    const int b = blockIdx.x, t = threadIdx.x;
    const int oo = t & 63, sc = t >> 6;
    float acc = 0.f;
    if (b < 64) {
        const float* p = kvPart + (size_t)sc * 128 * 4096 + b * 64 + oo;
#pragma unroll 8
        for (int s = 0; s < GRID1 / 4; ++s) acc += p[(size_t)s * 4096];
    } else {
        const float* p = ksPart + (size_t)sc * (GRID1) * 64 + oo;   // 4*GRID1 rows of 64 total
#pragma unroll 8
        for (int s = 0; s < GRID1; ++s) acc += p[(size_t)s * 64];
    }
    red[sc][oo] = acc;
    __syncthreads();
    if (t < 64) {
        float s = red[0][t] + red[1][t] + red[2][t] + red[3][t];
        if (b < 64) kvFin[b * 64 + t] = s;
        else        ksFin[t] = s;
    }
}

__global__ __launch_bounds__(256, 4) void pass2_kernel(
    const float* __restrict__ x, const float* __restrict__ Wq, const float* __restrict__ bq,
    const float* __restrict__ kvFin, const float* __restrict__ ksFin,
    float* __restrict__ out)
{
    __shared__ unsigned short qpL[64][72];     // qp staging [n][m]
    __shared__ unsigned short wqF[8][64][8];   // Wq B-frags
    __shared__ unsigned short kvF[8][64][8];   // kv B-frags

    const int tid = threadIdx.x;
    const int w = tid >> 6, l = tid & 63, l15 = l & 15, lg = l >> 4;

    // weight + kv frags from global (wave w builds j = w)
#pragma unroll
    for (int kk = 0; kk < 2; ++kk) {
        short8 f = load_bfrag(Wq, kk, lg, w * 16 + l15);
        *(short8*)&wqF[w * 2 + kk][l][0] = f;
        short8 g = load_bfrag(kvFin, kk, lg, w * 16 + l15);
        *(short8*)&kvF[w * 2 + kk][l][0] = g;
    }
    float bql[4], ksl[4];
#pragma unroll
    for (int j = 0; j < 4; ++j) { bql[j] = bq[j * 16 + l15]; ksl[j] = ksFin[j * 16 + l15]; }

    lds_barrier();   // frags ready

    const int t0 = blockIdx.x * TPB2;
    const float* xbase = x + ((size_t)t0 * 64 + w * 16 + l15) * 64 + lg * 8;
    float4 c0 = *(const float4*)(xbase + 0);
    float4 c1 = *(const float4*)(xbase + 4);
    float4 c2 = *(const float4*)(xbase + 32);
    float4 c3 = *(const float4*)(xbase + 36);

    for (int t = 0; t < TPB2; ++t) {
        const float* xn = xbase + (size_t)((t + 1 < TPB2) ? (t + 1) : t) * 4096;
        float4 n0 = *(const float4*)(xn + 0);
        float4 n1 = *(const float4*)(xn + 4);
        float4 n2 = *(const float4*)(xn + 32);
        float4 n3 = *(const float4*)(xn + 36);

        short8 a0 = cvt8(c0, c1);
        short8 a1 = cvt8(c2, c3);

        float qp[4][4];
#pragma unroll
        for (int j = 0; j < 4; ++j) {
            short8 bq0 = *(const short8*)&wqF[j * 2 + 0][l][0];
            short8 bq1 = *(const short8*)&wqF[j * 2 + 1][l][0];
            f32x4 z = (f32x4){0.f, 0.f, 0.f, 0.f};
            f32x4 aq = __builtin_amdgcn_mfma_f32_16x16x32_bf16(a0, bq0, z, 0, 0, 0);
            aq = __builtin_amdgcn_mfma_f32_16x16x32_bf16(a1, bq1, aq, 0, 0, 0);
#pragma unroll
            for (int r = 0; r < 4; ++r) qp[j][r] = fmaxf(aq[r] + bql[j], 0.f) + EPS;
        }
        // denom[row] = sum_m qp[row][m]*ksum[m]; butterfly across the 16 col-lanes
        float dp[4];
#pragma unroll
        for (int r = 0; r < 4; ++r)
            dp[r] = qp[0][r] * ksl[0] + qp[1][r] * ksl[1] + qp[2][r] * ksl[2] + qp[3][r] * ksl[3];
#pragma unroll
        for (int mask = 1; mask <= 8; mask <<= 1)
#pragma unroll
            for (int r = 0; r < 4; ++r) dp[r] += __shfl_xor(dp[r], mask, 64);

        const int nb = w * 16 + lg * 4;
#pragma unroll
        for (int j = 0; j < 4; ++j)
#pragma unroll
            for (int r = 0; r < 4; ++r)
                qpL[nb + r][j * 16 + l15] = f2bf(qp[j][r]);
        lds_barrier();

        short8 an0 = *(const short8*)&qpL[w * 16 + l15][lg * 8];
        short8 an1 = *(const short8*)&qpL[w * 16 + l15][32 + lg * 8];
        float inv[4];
#pragma unroll
        for (int r = 0; r < 4; ++r) inv[r] = __builtin_amdgcn_rcpf(dp[r]);
        const int row0 = (t0 + t) * 64 + w * 16;
#pragma unroll
        for (int j = 0; j < 4; ++j) {
            short8 kv0 = *(const short8*)&kvF[j * 2 + 0][l][0];
            short8 kv1 = *(const short8*)&kvF[j * 2 + 1][l][0];
            f32x4 z = (f32x4){0.f, 0.f, 0.f, 0.f};
            f32x4 nm = __builtin_amdgcn_mfma_f32_16x16x32_bf16(an0, kv0, z, 0, 0, 0);
            nm = __builtin_amdgcn_mfma_f32_16x16x32_bf16(an1, kv1, nm, 0, 0, 0);
#pragma unroll
            for (int r = 0; r < 4; ++r)
                out[(size_t)(row0 + lg * 4 + r) * 64 + j * 16 + l15] = nm[r] * inv[r];
        }
        lds_barrier();
        c0 = n0; c1 = n1; c2 = n2; c3 = n3;
    }
}

extern "C" void kernel_launch(void* const* d_in, const int* in_sizes, int n_in,
                              void* d_out, int out_size, void* d_ws, size_t ws_size,
                              hipStream_t stream)
{
    const float* x  = (const float*)d_in[0];
    const float* Wq = (const float*)d_in[1];
    const float* bq = (const float*)d_in[2];
    const float* Wk = (const float*)d_in[3];
    const float* bk = (const float*)d_in[4];
    const float* Wv = (const float*)d_in[5];
    const float* bv = (const float*)d_in[6];
    float* out = (float*)d_out;

    float* kvPart = (float*)d_ws;                              // [512][4096]
    float* ksPart = kvPart + (size_t)GRID1 * 4096;             // [512][4][64]
    float* kvFin  = ksPart + (size_t)GRID1 * 256;              // [4096]
    float* ksFin  = kvFin + 4096;                              // [64]

    hipLaunchKernelGGL(pass1_kernel, dim3(GRID1), dim3(256), 0, stream,
                       x, Wk, bk, Wv, bv, kvPart, ksPart);
    hipLaunchKernelGGL(reduce_kernel, dim3(65), dim3(256), 0, stream,
                       kvPart, ksPart, kvFin, ksFin);
    hipLaunchKernelGGL(pass2_kernel, dim3(GRID2), dim3(256), 0, stream,
                       x, Wq, bq, kvFin, ksFin, out);
}